// Round 12
// baseline (1780.116 us; speedup 1.0000x reference)
//
#include <hip/hip_runtime.h>
#include <hip/hip_bf16.h>
#include <stdint.h>

#define NLAYERS 8
#define LSEQ 576
#define EMB 768
#define NHEAD 12
#define HDIM 64
#define FFDIM 3072
#define BLROWS 4608   // B*L

typedef __attribute__((ext_vector_type(8))) short short8;
typedef __attribute__((ext_vector_type(4))) short short4v;
typedef __attribute__((ext_vector_type(4))) float floatx4;

__device__ __forceinline__ float b2f(short s) {
    union { float f; uint32_t u; } x; x.u = ((uint32_t)(uint16_t)s) << 16; return x.f;
}
__device__ __forceinline__ short f2b(float f) {
    union { float f; uint32_t u; } x; x.f = f;
    uint32_t r = x.u + 0x7fffu + ((x.u >> 16) & 1u);
    return (short)(r >> 16);
}

#define GLDS16(gp, lp) __builtin_amdgcn_global_load_lds( \
    (const __attribute__((address_space(1))) void*)(gp), \
    (__attribute__((address_space(3))) void*)(lp), 16, 0, 0)

// bijective XCD-chunked remap (m204)
__device__ __forceinline__ void xcd_remap(int& bx, int& by) {
    const int gx = gridDim.x;
    const int n  = gx * gridDim.y;
    const int orig = by * gx + bx;
    const int q = n >> 3, r = n & 7;
    const int xcd = orig & 7;
    const int wgid = (xcd < r ? xcd * (q + 1) : r * (q + 1) + (xcd - r) * q) + (orig >> 3);
    bx = wgid % gx;
    by = wgid / gx;
}

// ---------------- GEMM: C[M,N] = A[M,K](bf16) * Bt[N,K]^T (bf16) + epilogue ----------------
// 64x128 tile, BK=64. DEPTH=2: dbuf + full-drain barrier. DEPTH=3: counted vmcnt(6) (T4).
// T2 swizzle via pre-swizzled global source (rule 21). 4 waves, 2x2 of 32x64 per wave.
// RES: 0 none, 1 f32 residual, 2 bf16 residual.
// OUTM: 0 bf16, 1 f32, 2 f32 + bf16 copy into aux_kp.
// QKV: split epilogue -> Q (Cout, stride 768), K -> aux_kp (swz), V -> aux_vt (transposed+swz).
// SPLITK: blockIdx.z selects K-half; raw f32 partial -> (z ? aux_kp : Cout); epilogue deferred.
template<int DEPTH, int RES, bool ADD_POS, bool LEAKY, int OUTM, bool QKV, bool SPLITK>
__global__ __launch_bounds__(256)
void gemm_bt(const short* __restrict__ A, const short* __restrict__ Bt,
             const float* __restrict__ bias, const float* __restrict__ pos,
             const void* __restrict__ res, void* __restrict__ Cout,
             short* __restrict__ aux_kp, short* __restrict__ aux_vt,
             int N, int K)
{
    __shared__ short As[DEPTH * 64 * 64];
    __shared__ short Bs[DEPTH * 128 * 64];
    int bx = blockIdx.x, by = blockIdx.y;
    xcd_remap(bx, by);
    const int t    = threadIdx.x;
    const int lane = t & 63;
    const int w    = t >> 6;
    const int m0   = by * 64;
    const int n0   = bx * 128;
    const int wm   = (w >> 1) * 32;
    const int wn   = (w & 1) * 64;

    const int klen  = SPLITK ? (K >> 1) : K;
    const int kbase = SPLITK ? blockIdx.z * klen : 0;

    floatx4 acc[2][4];
#pragma unroll
    for (int i = 0; i < 2; ++i)
#pragma unroll
        for (int j = 0; j < 4; ++j)
            acc[i][j] = (floatx4){0.f, 0.f, 0.f, 0.f};

    const int srow = t >> 3;
    const int sch  = t & 7;
    const short* Ag = A  + (size_t)m0 * K + kbase;
    const short* Bg = Bt + (size_t)n0 * K + kbase;
    const int nt = klen >> 6;

#define STAGE(buf, k0)                                                              \
    {                                                                               \
        _Pragma("unroll")                                                           \
        for (int i = 0; i < 2; ++i) {                                               \
            int row = srow + i * 32;                                                \
            GLDS16(Ag + (size_t)row * K + (k0) + ((sch ^ (row & 7)) << 3),          \
                   &As[(buf) * 4096 + (size_t)(t + i * 256) * 8]);                  \
        }                                                                           \
        _Pragma("unroll")                                                           \
        for (int i = 0; i < 4; ++i) {                                               \
            int row = srow + i * 32;                                                \
            GLDS16(Bg + (size_t)row * K + (k0) + ((sch ^ (row & 7)) << 3),          \
                   &Bs[(buf) * 8192 + (size_t)(t + i * 256) * 8]);                  \
        }                                                                           \
    }

#define COMPUTE(buf)                                                                \
    {                                                                               \
        _Pragma("unroll")                                                           \
        for (int ks = 0; ks < 2; ++ks) {                                            \
            short8 af[2], bf[4];                                                    \
            _Pragma("unroll")                                                       \
            for (int i = 0; i < 2; ++i) {                                           \
                int row = wm + i * 16 + (lane & 15);                                \
                int ch  = (ks * 4 + (lane >> 4)) ^ (row & 7);                       \
                af[i] = *(const short8*)&As[(buf) * 4096 + row * 64 + ch * 8];      \
            }                                                                       \
            _Pragma("unroll")                                                       \
            for (int j = 0; j < 4; ++j) {                                           \
                int row = wn + j * 16 + (lane & 15);                                \
                int ch  = (ks * 4 + (lane >> 4)) ^ (row & 7);                       \
                bf[j] = *(const short8*)&Bs[(buf) * 8192 + row * 64 + ch * 8];      \
            }                                                                       \
            _Pragma("unroll")                                                       \
            for (int i = 0; i < 2; ++i)                                             \
                _Pragma("unroll")                                                   \
                for (int j = 0; j < 4; ++j)                                         \
                    acc[i][j] = __builtin_amdgcn_mfma_f32_16x16x32_bf16(            \
                        af[i], bf[j], acc[i][j], 0, 0, 0);                          \
        }                                                                           \
    }

    if constexpr (DEPTH == 2) {
        STAGE(0, 0);
        __syncthreads();
        int cur = 0;
        for (int k0 = 0; k0 < klen; k0 += 64) {
            if (k0 + 64 < klen) STAGE(cur ^ 1, k0 + 64);
            COMPUTE(cur);
            __syncthreads();
            cur ^= 1;
        }
    } else {
        STAGE(0, 0);
        STAGE(1, 64);
        asm volatile("s_waitcnt vmcnt(6)" ::: "memory");
        __builtin_amdgcn_sched_barrier(0);
        __builtin_amdgcn_s_barrier();
        int cur = 0, stg = 2;
        for (int tt = 0; tt < nt; ++tt) {
            if (tt + 2 < nt) STAGE(stg, (tt + 2) << 6);
            COMPUTE(cur);
            if (tt + 1 < nt) {
                if (tt + 2 < nt) { asm volatile("s_waitcnt vmcnt(6)" ::: "memory"); }
                else             { asm volatile("s_waitcnt vmcnt(0)" ::: "memory"); }
                __builtin_amdgcn_sched_barrier(0);
                __builtin_amdgcn_s_barrier();
                __builtin_amdgcn_sched_barrier(0);
            }
            cur = (cur + 1 == DEPTH) ? 0 : cur + 1;
            stg = (stg + 1 == DEPTH) ? 0 : stg + 1;
        }
    }
#undef STAGE
#undef COMPUTE

    const int colb = n0 + wn + (lane & 15);
    const int rowb = m0 + wm + ((lane >> 4) * 4);

    if constexpr (SPLITK) {
        float* P = blockIdx.z ? (float*)aux_kp : (float*)Cout;
#pragma unroll
        for (int i = 0; i < 2; ++i)
#pragma unroll
            for (int j = 0; j < 4; ++j)
#pragma unroll
                for (int r = 0; r < 4; ++r)
                    P[(size_t)(rowb + i * 16 + r) * N + colb + j * 16] = acc[i][j][r];
        return;
    }

#pragma unroll
    for (int i = 0; i < 2; ++i) {
#pragma unroll
        for (int j = 0; j < 4; ++j) {
            const int col = colb + j * 16;
            const float bv = bias[col];
#pragma unroll
            for (int r = 0; r < 4; ++r) {
                const int row = rowb + i * 16 + r;
                float v = acc[i][j][r] + bv;
                if constexpr (ADD_POS) v += pos[(size_t)(row % LSEQ) * N + col];
                if constexpr (RES == 1) v += ((const float*)res)[(size_t)row * N + col];
                if constexpr (RES == 2) v += b2f(((const short*)res)[(size_t)row * N + col]);
                if constexpr (LEAKY)   v = v >= 0.f ? v : 0.01f * v;
                if constexpr (QKV) {
                    const int b = row / LSEQ, l = row % LSEQ;
                    const short sv16 = f2b(v);
                    if (col < 768) {
                        ((short*)Cout)[(size_t)row * 768 + col] = sv16;
                    } else if (col < 1536) {
                        const int d = col - 768, hh = d >> 6, dd = d & 63;
                        const size_t bh = (size_t)b * 12 + hh;
                        aux_kp[(bh * LSEQ + l) * 64 + (dd & 7) + (((dd >> 3) ^ (l & 7)) << 3)] = sv16;
                    } else {
                        const int d = col - 1536, hh = d >> 6, dd = d & 63;
                        const size_t bh = (size_t)b * 12 + hh;
                        aux_vt[(bh * 64 + dd) * LSEQ + (l & ~63) + ((l & 63) ^ ((dd & 7) << 3))] = sv16;
                    }
                } else if constexpr (OUTM == 1) {
                    ((float*)Cout)[(size_t)row * N + col] = v;
                } else if constexpr (OUTM == 2) {
                    ((float*)Cout)[(size_t)row * N + col] = v;
                    aux_kp[(size_t)row * N + col] = f2b(v);
                } else {
                    ((short*)Cout)[(size_t)row * N + col] = f2b(v);
                }
            }
        }
    }
}

// ---------------- split-K combine + full epilogue (N=768 shapes). 4 el/thread ----------------
// RES: 0/1/2 as above. OUTM: 1 f32 out, 2 f32 + bf16 copy.
template<int RES, bool ADD_POS, int OUTM>
__global__ __launch_bounds__(256)
void combinek(const float* __restrict__ P0, const float* __restrict__ P1,
              const float* __restrict__ bias, const float* __restrict__ pos,
              const void* __restrict__ res, float* __restrict__ out,
              short* __restrict__ auxb)
{
    const size_t i4 = ((size_t)blockIdx.x * 256 + threadIdx.x) * 4;   // < 4608*768
    const int row = (int)(i4 / 768);
    const int col = (int)(i4 % 768);
    floatx4 a = *(const floatx4*)&P0[i4];
    floatx4 b = *(const floatx4*)&P1[i4];
    floatx4 bv = *(const floatx4*)&bias[col];
    floatx4 v;
#pragma unroll
    for (int j = 0; j < 4; ++j) v[j] = a[j] + b[j] + bv[j];
    if constexpr (ADD_POS) {
        floatx4 p = *(const floatx4*)&pos[(size_t)(row % LSEQ) * 768 + col];
#pragma unroll
        for (int j = 0; j < 4; ++j) v[j] += p[j];
    }
    if constexpr (RES == 1) {
        floatx4 rr = *(const floatx4*)&((const float*)res)[i4];
#pragma unroll
        for (int j = 0; j < 4; ++j) v[j] += rr[j];
    }
    if constexpr (RES == 2) {
        short4v rr = *(const short4v*)&((const short*)res)[i4];
#pragma unroll
        for (int j = 0; j < 4; ++j) v[j] += b2f(rr[j]);
    }
    *(floatx4*)&out[i4] = v;
    if constexpr (OUTM == 2) {
        short4v ob;
#pragma unroll
        for (int j = 0; j < 4; ++j) ob[j] = f2b(v[j]);
        *(short4v*)&auxb[i4] = ob;
    }
}

// ---------------- LayerNorm over E=768, input f32, output bf16 ----------------
__global__ __launch_bounds__(256)
void ln_kernel(const float* __restrict__ h, const float* __restrict__ g,
               const float* __restrict__ bbias, short* __restrict__ outb)
{
    const int row = blockIdx.x;
    const float* x = h + (size_t)row * EMB;
    const int t = threadIdx.x;
    float v0 = x[t], v1 = x[t + 256], v2 = x[t + 512];
    float s  = v0 + v1 + v2;
    float ss = v0 * v0 + v1 * v1 + v2 * v2;
#pragma unroll
    for (int m = 1; m < 64; m <<= 1) {
        s  += __shfl_xor(s, m, 64);
        ss += __shfl_xor(ss, m, 64);
    }
    __shared__ float red[8];
    if ((t & 63) == 0) { red[t >> 6] = s; red[4 + (t >> 6)] = ss; }
    __syncthreads();
    float S  = red[0] + red[1] + red[2] + red[3];
    float SS = red[4] + red[5] + red[6] + red[7];
    float mean = S * (1.f / 768.f);
    float var  = SS * (1.f / 768.f) - mean * mean;
    float rstd = rsqrtf(var + 1e-5f);
    const size_t base = (size_t)row * EMB;
#pragma unroll
    for (int q = 0; q < 3; ++q) {
        int e = t + q * 256;
        float v = (q == 0 ? v0 : (q == 1 ? v1 : v2));
        float y = (v - mean) * rstd * g[e] + bbias[e];
        outb[base + e] = f2b(y);
    }
}

// ---------------- MFMA flash attention. grid (9 qtiles, 96 bh), block 256 = 4 waves ----------------
__global__ __launch_bounds__(256)
void attn_mfma(const short* __restrict__ qbuf, const short* __restrict__ kp,
               const short* __restrict__ vt, short* __restrict__ oout, int causal)
{
    const int qt = blockIdx.x, bh = blockIdx.y;
    const int b = bh / 12, h = bh % 12;
    const int t = threadIdx.x, lane = t & 63, w = t >> 6;

    __shared__ short Ks[64 * 64];
    __shared__ short Vs[64 * 64];
    __shared__ short Plds[4][16][72];

    const int nrow = lane & 15;
    const int kch  = (lane >> 4) * 8;
    const int swz  = (lane & 7) << 3;

    short8 aq[2];
    {
        const short* qrow = qbuf + ((size_t)(b * LSEQ) + qt * 64 + w * 16 + nrow) * 768 + h * 64 + kch;
        aq[0] = *(const short8*)qrow;
        aq[1] = *(const short8*)(qrow + 32);
    }

    float m[4], lsum[4];
    floatx4 oacc[4];
#pragma unroll
    for (int r = 0; r < 4; ++r) { m[r] = -3e38f; lsum[r] = 0.f; }
#pragma unroll
    for (int j = 0; j < 4; ++j) oacc[j] = (floatx4){0.f, 0.f, 0.f, 0.f};

    const int ktend = causal ? qt : 8;
    const short* ksrc = kp + ((size_t)bh * LSEQ) * 64;
    const short* vsrc = vt + ((size_t)bh * 64) * LSEQ;

    for (int kt = 0; kt <= ktend; ++kt) {
        __syncthreads();
        {
            const short* kt_src = ksrc + (size_t)(kt * 64) * 64;
            GLDS16(kt_src + (size_t)t * 8,          &Ks[(size_t)t * 8]);
            GLDS16(kt_src + (size_t)(t + 256) * 8,  &Ks[(size_t)(t + 256) * 8]);
            int f0 = t, f1 = t + 256;
            GLDS16(vsrc + (size_t)(f0 >> 3) * LSEQ + kt * 64 + (f0 & 7) * 8, &Vs[(size_t)f0 * 8]);
            GLDS16(vsrc + (size_t)(f1 >> 3) * LSEQ + kt * 64 + (f1 & 7) * 8, &Vs[(size_t)f1 * 8]);
        }
        __syncthreads();

        floatx4 sc[4];
#pragma unroll
        for (int j = 0; j < 4; ++j) sc[j] = (floatx4){0.f, 0.f, 0.f, 0.f};
#pragma unroll
        for (int s = 0; s < 2; ++s) {
#pragma unroll
            for (int j = 0; j < 4; ++j) {
                short8 bk = *(const short8*)&Ks[(16 * j + nrow) * 64 + ((kch + 32 * s) ^ swz)];
                sc[j] = __builtin_amdgcn_mfma_f32_16x16x32_bf16(aq[s], bk, sc[j], 0, 0, 0);
            }
        }
        float sv[4][4];
#pragma unroll
        for (int j = 0; j < 4; ++j)
#pragma unroll
            for (int r = 0; r < 4; ++r) {
                float v = sc[j][r] * 0.125f;
                if (causal && kt == qt) {
                    int key = kt * 64 + 16 * j + nrow;
                    int qr  = qt * 64 + w * 16 + (lane >> 4) * 4 + r;
                    if (key > qr) v = -1e12f;
                }
                sv[j][r] = v;
            }
#pragma unroll
        for (int r = 0; r < 4; ++r) {
            float tm = fmaxf(fmaxf(sv[0][r], sv[1][r]), fmaxf(sv[2][r], sv[3][r]));
            tm = fmaxf(tm, __shfl_xor(tm, 1, 64));
            tm = fmaxf(tm, __shfl_xor(tm, 2, 64));
            tm = fmaxf(tm, __shfl_xor(tm, 4, 64));
            tm = fmaxf(tm, __shfl_xor(tm, 8, 64));
            float nm = fmaxf(m[r], tm);
            float c  = __expf(m[r] - nm);
            m[r] = nm;
            float ps = 0.f;
#pragma unroll
            for (int j = 0; j < 4; ++j) {
                float p = __expf(sv[j][r] - nm);
                sv[j][r] = p;
                ps += p;
            }
            lsum[r] = lsum[r] * c + ps;
#pragma unroll
            for (int j = 0; j < 4; ++j) oacc[j][r] *= c;
        }
#pragma unroll
        for (int j = 0; j < 4; ++j)
#pragma unroll
            for (int r = 0; r < 4; ++r)
                Plds[w][(lane >> 4) * 4 + r][16 * j + nrow] = f2b(sv[j][r]);
        short8 ap[2];
#pragma unroll
        for (int s = 0; s < 2; ++s)
            ap[s] = *(const short8*)&Plds[w][nrow][kch + 32 * s];
#pragma unroll
        for (int s = 0; s < 2; ++s) {
#pragma unroll
            for (int j = 0; j < 4; ++j) {
                short8 bv = *(const short8*)&Vs[(16 * j + nrow) * 64 + ((kch + 32 * s) ^ swz)];
                oacc[j] = __builtin_amdgcn_mfma_f32_16x16x32_bf16(ap[s], bv, oacc[j], 0, 0, 0);
            }
        }
    }

    float inv[4];
#pragma unroll
    for (int r = 0; r < 4; ++r) {
        float L = lsum[r];
        L += __shfl_xor(L, 1, 64);
        L += __shfl_xor(L, 2, 64);
        L += __shfl_xor(L, 4, 64);
        L += __shfl_xor(L, 8, 64);
        inv[r] = 1.f / L;
    }
#pragma unroll
    for (int j = 0; j < 4; ++j)
#pragma unroll
        for (int r = 0; r < 4; ++r) {
            size_t lq = (size_t)qt * 64 + w * 16 + (lane >> 4) * 4 + r;
            oout[((size_t)bh * LSEQ + lq) * 64 + 16 * j + nrow] = f2b(oacc[j][r] * inv[r]);
        }
}

// ---------------- transposes ----------------
__global__ void transpose_f2b(const float* __restrict__ in, short* __restrict__ out,
                              int R, int C, long long ibs, long long obs)
{
    __shared__ float tile[32][33];
    const int b = blockIdx.z;
    const float* inb = in + (long long)b * ibs;
    short* outb = out + (long long)b * obs;
    const int r0 = blockIdx.y * 32, c0 = blockIdx.x * 32;
    const int tx = threadIdx.x, ty = threadIdx.y;
#pragma unroll
    for (int i = 0; i < 32; i += 8) tile[ty + i][tx] = inb[(size_t)(r0 + ty + i) * C + c0 + tx];
    __syncthreads();
#pragma unroll
    for (int i = 0; i < 32; i += 8) outb[(size_t)(c0 + ty + i) * R + r0 + tx] = f2b(tile[tx][ty + i]);
}

__global__ void transpose_f2f(const float* __restrict__ in, float* __restrict__ out,
                              int R, int C, long long ibs, long long obs)
{
    __shared__ float tile[32][33];
    const int b = blockIdx.z;
    const float* inb = in + (long long)b * ibs;
    float* outb = out + (long long)b * obs;
    const int r0 = blockIdx.y * 32, c0 = blockIdx.x * 32;
    const int tx = threadIdx.x, ty = threadIdx.y;
#pragma unroll
    for (int i = 0; i < 32; i += 8) tile[ty + i][tx] = inb[(size_t)(r0 + ty + i) * C + c0 + tx];
    __syncthreads();
#pragma unroll
    for (int i = 0; i < 32; i += 8) outb[(size_t)(c0 + ty + i) * R + r0 + tx] = tile[tx][ty + i];
}

// ---------------- misc small kernels ----------------
__global__ void concat_qkv_bias(const float* __restrict__ bq, const float* __restrict__ bk,
                                const float* __restrict__ bv, float* __restrict__ out)
{
    int i = blockIdx.x * 256 + threadIdx.x;
    int layer = i / 2304, j = i % 2304;
    float v;
    if (j < 768)       v = bq[layer * 768 + j];
    else if (j < 1536) v = bk[layer * 768 + j - 768];
    else               v = bv[layer * 768 + j - 1536];
    out[i] = v;
}

__global__ void im2col_kernel(const float* __restrict__ x, short* __restrict__ xcol)
{
    const size_t idx = (size_t)blockIdx.x * 256 + threadIdx.x;
    const int k = (int)(idx % 768);
    const size_t m = idx / 768;
    const int c  = k >> 8;
    const int ky = (k >> 4) & 15;
    const int kx = k & 15;
    const int b  = (int)(m / 576);
    const int l  = (int)(m % 576);
    const int ph = l / 24, pw = l % 24;
    xcol[idx] = f2b(x[((size_t)(b * 3 + c) * 384 + ph * 16 + ky) * 384 + pw * 16 + kx]);
}

__global__ void cast_f32_b16(const float* __restrict__ in, short* __restrict__ out, int n)
{
    int i = blockIdx.x * 256 + threadIdx.x;
    if (i < n) out[i] = f2b(in[i]);
}

// ---------------- host launcher ----------------
extern "C" void kernel_launch(void* const* d_in, const int* in_sizes, int n_in,
                              void* d_out, int out_size, void* d_ws, size_t ws_size,
                              hipStream_t stream)
{
    const float* x      = (const float*)d_in[0];
    const float* conv_w = (const float*)d_in[1];
    const float* conv_b = (const float*)d_in[2];
    const float* pos    = (const float*)d_in[3];
    const float* ln0_s  = (const float*)d_in[4];
    const float* ln0_b  = (const float*)d_in[5];
    const float* Wq     = (const float*)d_in[6];
    const float* bq     = (const float*)d_in[7];
    const float* Wk     = (const float*)d_in[8];
    const float* bk     = (const float*)d_in[9];
    const float* Wv     = (const float*)d_in[10];
    const float* bv     = (const float*)d_in[11];
    const float* Wo     = (const float*)d_in[12];
    const float* bo     = (const float*)d_in[13];
    const float* ln1_s  = (const float*)d_in[14];
    const float* ln1_b  = (const float*)d_in[15];
    const float* W1     = (const float*)d_in[16];
    const float* b1     = (const float*)d_in[17];
    const float* W2     = (const float*)d_in[18];
    const float* b2     = (const float*)d_in[19];
    const float* proj_w = (const float*)d_in[20];
    const float* proj_b = (const float*)d_in[21];

    char* ws = (char*)d_ws;
    short* qkvT  = (short*)(ws);                    // [8][2304][768] bf16
    short* woT   = (short*)(ws + 28311552);         // [8][768][768]
    short* w1T   = (short*)(ws + 37748736);         // [8][3072][768]
    short* w2T   = (short*)(ws + 75497472);         // [8][768][3072]
    short* projT = (short*)(ws + 113246208);        // [768][768]
    float* qkvb  = (float*)(ws + 114425856);        // [8][2304] f32
    short* tmpA  = (short*)(ws + 114499584);        // xcol / m1 bf16 [4608][3072]; kp/vt overlay; P0 site
    float* h     = (float*)(ws + 142811136);        // residual stream f32 [4608][768]
    short* xn    = (short*)(ws + 156966912);        // LN0 out bf16; hb at end
    short* xrb   = (short*)(ws + 164044800);        // LN1 out bf16
    short* qbuf  = (short*)(ws + 185278464);        // Q [4608][768] bf16; P1 (f32) overlay
    short* o     = (short*)(ws + 206512128);        // attn out (scrambled) bf16
    short* convB = (short*)(ws + 213590016);        // conv_w cast bf16 [768][768]

    short* kp = tmpA;                               // [96][576][64] bf16 (overlay)
    short* vt = tmpA + 3538944;                     // [96][64][576] bf16
    float* P1 = (float*)qbuf;                       // split-K partial 1 (qbuf dead at those points)
    float* tmpAF = (float*)tmpA;

    dim3 tb(32, 8);
    transpose_f2b<<<dim3(24, 24, 8), tb, 0, stream>>>(Wq, qkvT,           768, 768, 589824, 1769472);
    transpose_f2b<<<dim3(24, 24, 8), tb, 0, stream>>>(Wk, qkvT + 589824,  768, 768, 589824, 1769472);
    transpose_f2b<<<dim3(24, 24, 8), tb, 0, stream>>>(Wv, qkvT + 1179648, 768, 768, 589824, 1769472);
    transpose_f2b<<<dim3(24, 24, 8), tb, 0, stream>>>(Wo, woT,            768, 768, 589824, 589824);
    transpose_f2b<<<dim3(96, 24, 8), tb, 0, stream>>>(W1, w1T,            768, 3072, 2359296, 2359296);
    transpose_f2b<<<dim3(24, 96, 8), tb, 0, stream>>>(W2, w2T,            3072, 768, 2359296, 2359296);
    transpose_f2b<<<dim3(24, 24, 1), tb, 0, stream>>>(proj_w, projT,      768, 768, 0, 0);
    cast_f32_b16<<<2304, 256, 0, stream>>>(conv_w, convB, 589824);
    concat_qkv_bias<<<72, 256, 0, stream>>>(bq, bk, bv, qkvb);

    // patch embed: im2col + split-K GEMM (P0=h, P1=qbuf) + combine(bias+pos) -> h
    im2col_kernel<<<13824, 256, 0, stream>>>(x, tmpA);
    gemm_bt<3, 0, false, false, 1, false, true><<<dim3(6, 72, 2), 256, 0, stream>>>(
        tmpA, convB, nullptr, nullptr, nullptr, h, (short*)P1, nullptr, 768, 768);
    combinek<0, true, 1><<<3456, 256, 0, stream>>>(h, P1, conv_b, pos, nullptr, h, nullptr);

    for (int i = 0; i < NLAYERS; ++i) {
        ln_kernel<<<4608, 256, 0, stream>>>(h, ln0_s + i * 768, ln0_b + i * 768, xn);
        // qkv GEMM with fused split epilogue: Q->qbuf, K->kp (swz), V->vt (transposed+swz)
        gemm_bt<2, 0, false, false, 0, true, false><<<dim3(18, 72), 256, 0, stream>>>(
            xn, qkvT + (size_t)i * 1769472, qkvb + i * 2304, nullptr, nullptr, qbuf, kp, vt, 2304, 768);
        attn_mfma<<<dim3(9, 96), 256, 0, stream>>>(qbuf, kp, vt, o, i == 0 ? 1 : 0);
        // Wo split-K: P0=tmpA (kp/vt dead), P1=qbuf (dead); combine adds f32 residual h -> h
        gemm_bt<3, 0, false, false, 1, false, true><<<dim3(6, 72, 2), 256, 0, stream>>>(
            o, woT + (size_t)i * 589824, nullptr, nullptr, nullptr, tmpAF, (short*)P1, nullptr, 768, 768);
        combinek<1, false, 1><<<3456, 256, 0, stream>>>(tmpAF, P1, bo + i * 768, nullptr, h, h, nullptr);
        ln_kernel<<<4608, 256, 0, stream>>>(h, ln1_s + i * 768, ln1_b + i * 768, xrb);
        gemm_bt<2, 0, false, true, 0, false, false><<<dim3(24, 72), 256, 0, stream>>>(
            xrb, w1T + (size_t)i * 2359296, b1 + i * 3072, nullptr, nullptr, tmpA, nullptr, nullptr, 3072, 768);
        // W2 split-K: P0=h (dead), P1=qbuf (dead); combine adds bf16 residual xrb -> h (+hb on last)
        gemm_bt<3, 0, false, false, 1, false, true><<<dim3(6, 72, 2), 256, 0, stream>>>(
            tmpA, w2T + (size_t)i * 2359296, nullptr, nullptr, nullptr, h, (short*)P1, nullptr, 768, 3072);
        if (i < NLAYERS - 1) {
            combinek<2, false, 1><<<3456, 256, 0, stream>>>(h, P1, b2 + i * 768, nullptr, xrb, h, nullptr);
        } else {
            combinek<2, false, 2><<<3456, 256, 0, stream>>>(h, P1, b2 + i * 768, nullptr, xrb, h, xn);
        }
    }

    // final projection (split-K, P0=h dead, P1=qbuf) + combine -> yf, then output scramble
    short* hb = xn;              // bf16 copy of final h (written by layer-7 W2 combine)
    float* yf = tmpAF;
    gemm_bt<3, 0, false, false, 1, false, true><<<dim3(6, 72, 2), 256, 0, stream>>>(
        hb, projT, nullptr, nullptr, nullptr, h, (short*)P1, nullptr, 768, 768);
    combinek<0, false, 1><<<3456, 256, 0, stream>>>(h, P1, proj_b, nullptr, nullptr, yf, nullptr);
    transpose_f2f<<<dim3(24, 18, 8), tb, 0, stream>>>(yf, (float*)d_out, 576, 768, 442368, 442368);
}

// Round 13
// 1647.898 us; speedup vs baseline: 1.0802x; 1.0802x over previous
//
#include <hip/hip_runtime.h>
#include <hip/hip_bf16.h>
#include <stdint.h>

#define NLAYERS 8
#define LSEQ 576
#define EMB 768
#define NHEAD 12
#define HDIM 64
#define FFDIM 3072
#define BLROWS 4608   // B*L

typedef __attribute__((ext_vector_type(8))) short short8;
typedef __attribute__((ext_vector_type(4))) float floatx4;

__device__ __forceinline__ float b2f(short s) {
    union { float f; uint32_t u; } x; x.u = ((uint32_t)(uint16_t)s) << 16; return x.f;
}
__device__ __forceinline__ short f2b(float f) {
    union { float f; uint32_t u; } x; x.f = f;
    uint32_t r = x.u + 0x7fffu + ((x.u >> 16) & 1u);
    return (short)(r >> 16);
}

#define GLDS16(gp, lp) __builtin_amdgcn_global_load_lds( \
    (const __attribute__((address_space(1))) void*)(gp), \
    (__attribute__((address_space(3))) void*)(lp), 16, 0, 0)

// bijective XCD-chunked remap (m204)
__device__ __forceinline__ void xcd_remap(int& bx, int& by) {
    const int gx = gridDim.x;
    const int n  = gx * gridDim.y;
    const int orig = by * gx + bx;
    const int q = n >> 3, r = n & 7;
    const int xcd = orig & 7;
    const int wgid = (xcd < r ? xcd * (q + 1) : r * (q + 1) + (xcd - r) * q) + (orig >> 3);
    bx = wgid % gx;
    by = wgid / gx;
}

// ---------------- GEMM: C[M,N] = A[M,K](bf16) * Bt[N,K]^T (bf16) + epilogue ----------------
// 64x128 tile, BK=64. DEPTH=2: dbuf + full-drain barrier. DEPTH=3: counted vmcnt(6) (T4).
// T2 swizzle via pre-swizzled global source (rule 21). 4 waves, 2x2 of 32x64 per wave.
// RES: 0 none, 1 f32 residual, 2 bf16 residual.
// OUTM: 0 bf16, 1 f32, 2 f32 + bf16 copy into aux_kp.
// QKV: split epilogue -> Q (Cout, stride 768), K -> aux_kp (swz), V -> aux_vt (transposed+swz).
template<int DEPTH, int RES, bool ADD_POS, bool LEAKY, int OUTM, bool QKV>
__global__ __launch_bounds__(256)
void gemm_bt(const short* __restrict__ A, const short* __restrict__ Bt,
             const float* __restrict__ bias, const float* __restrict__ pos,
             const void* __restrict__ res, void* __restrict__ Cout,
             short* __restrict__ aux_kp, short* __restrict__ aux_vt,
             int N, int K)
{
    __shared__ short As[DEPTH * 64 * 64];
    __shared__ short Bs[DEPTH * 128 * 64];
    int bx = blockIdx.x, by = blockIdx.y;
    xcd_remap(bx, by);
    const int t    = threadIdx.x;
    const int lane = t & 63;
    const int w    = t >> 6;
    const int m0   = by * 64;
    const int n0   = bx * 128;
    const int wm   = (w >> 1) * 32;
    const int wn   = (w & 1) * 64;

    floatx4 acc[2][4];
#pragma unroll
    for (int i = 0; i < 2; ++i)
#pragma unroll
        for (int j = 0; j < 4; ++j)
            acc[i][j] = (floatx4){0.f, 0.f, 0.f, 0.f};

    const int srow = t >> 3;
    const int sch  = t & 7;
    const short* Ag = A  + (size_t)m0 * K;
    const short* Bg = Bt + (size_t)n0 * K;
    const int nt = K >> 6;

#define STAGE(buf, k0)                                                              \
    {                                                                               \
        _Pragma("unroll")                                                           \
        for (int i = 0; i < 2; ++i) {                                               \
            int row = srow + i * 32;                                                \
            GLDS16(Ag + (size_t)row * K + (k0) + ((sch ^ (row & 7)) << 3),          \
                   &As[(buf) * 4096 + (size_t)(t + i * 256) * 8]);                  \
        }                                                                           \
        _Pragma("unroll")                                                           \
        for (int i = 0; i < 4; ++i) {                                               \
            int row = srow + i * 32;                                                \
            GLDS16(Bg + (size_t)row * K + (k0) + ((sch ^ (row & 7)) << 3),          \
                   &Bs[(buf) * 8192 + (size_t)(t + i * 256) * 8]);                  \
        }                                                                           \
    }

#define COMPUTE(buf)                                                                \
    {                                                                               \
        _Pragma("unroll")                                                           \
        for (int ks = 0; ks < 2; ++ks) {                                            \
            short8 af[2], bf[4];                                                    \
            _Pragma("unroll")                                                       \
            for (int i = 0; i < 2; ++i) {                                           \
                int row = wm + i * 16 + (lane & 15);                                \
                int ch  = (ks * 4 + (lane >> 4)) ^ (row & 7);                       \
                af[i] = *(const short8*)&As[(buf) * 4096 + row * 64 + ch * 8];      \
            }                                                                       \
            _Pragma("unroll")                                                       \
            for (int j = 0; j < 4; ++j) {                                           \
                int row = wn + j * 16 + (lane & 15);                                \
                int ch  = (ks * 4 + (lane >> 4)) ^ (row & 7);                       \
                bf[j] = *(const short8*)&Bs[(buf) * 8192 + row * 64 + ch * 8];      \
            }                                                                       \
            _Pragma("unroll")                                                       \
            for (int i = 0; i < 2; ++i)                                             \
                _Pragma("unroll")                                                   \
                for (int j = 0; j < 4; ++j)                                         \
                    acc[i][j] = __builtin_amdgcn_mfma_f32_16x16x32_bf16(            \
                        af[i], bf[j], acc[i][j], 0, 0, 0);                          \
        }                                                                           \
    }

    if constexpr (DEPTH == 2) {
        STAGE(0, 0);
        __syncthreads();
        int cur = 0;
        for (int k0 = 0; k0 < K; k0 += 64) {
            if (k0 + 64 < K) STAGE(cur ^ 1, k0 + 64);
            COMPUTE(cur);
            __syncthreads();
            cur ^= 1;
        }
    } else {
        STAGE(0, 0);
        STAGE(1, 64);
        asm volatile("s_waitcnt vmcnt(6)" ::: "memory");
        __builtin_amdgcn_sched_barrier(0);
        __builtin_amdgcn_s_barrier();
        int cur = 0, stg = 2;
        for (int tt = 0; tt < nt; ++tt) {
            if (tt + 2 < nt) STAGE(stg, (tt + 2) << 6);
            COMPUTE(cur);
            if (tt + 1 < nt) {
                if (tt + 2 < nt) { asm volatile("s_waitcnt vmcnt(6)" ::: "memory"); }
                else             { asm volatile("s_waitcnt vmcnt(0)" ::: "memory"); }
                __builtin_amdgcn_sched_barrier(0);
                __builtin_amdgcn_s_barrier();
                __builtin_amdgcn_sched_barrier(0);
            }
            cur = (cur + 1 == DEPTH) ? 0 : cur + 1;
            stg = (stg + 1 == DEPTH) ? 0 : stg + 1;
        }
    }
#undef STAGE
#undef COMPUTE

    const int colb = n0 + wn + (lane & 15);
    const int rowb = m0 + wm + ((lane >> 4) * 4);
#pragma unroll
    for (int i = 0; i < 2; ++i) {
#pragma unroll
        for (int j = 0; j < 4; ++j) {
            const int col = colb + j * 16;
            const float bv = bias[col];
#pragma unroll
            for (int r = 0; r < 4; ++r) {
                const int row = rowb + i * 16 + r;
                float v = acc[i][j][r] + bv;
                if constexpr (ADD_POS) v += pos[(size_t)(row % LSEQ) * N + col];
                if constexpr (RES == 1) v += ((const float*)res)[(size_t)row * N + col];
                if constexpr (RES == 2) v += b2f(((const short*)res)[(size_t)row * N + col]);
                if constexpr (LEAKY)   v = v >= 0.f ? v : 0.01f * v;
                if constexpr (QKV) {
                    const int b = row / LSEQ, l = row % LSEQ;
                    const short sv16 = f2b(v);
                    if (col < 768) {
                        ((short*)Cout)[(size_t)row * 768 + col] = sv16;
                    } else if (col < 1536) {
                        const int d = col - 768, hh = d >> 6, dd = d & 63;
                        const size_t bh = (size_t)b * 12 + hh;
                        aux_kp[(bh * LSEQ + l) * 64 + (dd & 7) + (((dd >> 3) ^ (l & 7)) << 3)] = sv16;
                    } else {
                        const int d = col - 1536, hh = d >> 6, dd = d & 63;
                        const size_t bh = (size_t)b * 12 + hh;
                        aux_vt[(bh * 64 + dd) * LSEQ + (l & ~63) + ((l & 63) ^ ((dd & 7) << 3))] = sv16;
                    }
                } else if constexpr (OUTM == 1) {
                    ((float*)Cout)[(size_t)row * N + col] = v;
                } else if constexpr (OUTM == 2) {
                    ((float*)Cout)[(size_t)row * N + col] = v;
                    aux_kp[(size_t)row * N + col] = f2b(v);
                } else {
                    ((short*)Cout)[(size_t)row * N + col] = f2b(v);
                }
            }
        }
    }
}

// ---------------- LayerNorm over E=768, input f32, output bf16 ----------------
__global__ __launch_bounds__(256)
void ln_kernel(const float* __restrict__ h, const float* __restrict__ g,
               const float* __restrict__ bbias, short* __restrict__ outb)
{
    const int row = blockIdx.x;
    const float* x = h + (size_t)row * EMB;
    const int t = threadIdx.x;
    float v0 = x[t], v1 = x[t + 256], v2 = x[t + 512];
    float s  = v0 + v1 + v2;
    float ss = v0 * v0 + v1 * v1 + v2 * v2;
#pragma unroll
    for (int m = 1; m < 64; m <<= 1) {
        s  += __shfl_xor(s, m, 64);
        ss += __shfl_xor(ss, m, 64);
    }
    __shared__ float red[8];
    if ((t & 63) == 0) { red[t >> 6] = s; red[4 + (t >> 6)] = ss; }
    __syncthreads();
    float S  = red[0] + red[1] + red[2] + red[3];
    float SS = red[4] + red[5] + red[6] + red[7];
    float mean = S * (1.f / 768.f);
    float var  = SS * (1.f / 768.f) - mean * mean;
    float rstd = rsqrtf(var + 1e-5f);
    const size_t base = (size_t)row * EMB;
#pragma unroll
    for (int q = 0; q < 3; ++q) {
        int e = t + q * 256;
        float v = (q == 0 ? v0 : (q == 1 ? v1 : v2));
        float y = (v - mean) * rstd * g[e] + bbias[e];
        outb[base + e] = f2b(y);
    }
}

// ---------------- MFMA flash attention, double-buffered K/V. grid (9, 96), 4 waves ----------------
// Per K-tile: prefetch t+1 -> compute t (QK^T, online softmax, PV) -> vmcnt(0)+barrier (1/tile).
__global__ __launch_bounds__(256)
void attn_mfma(const short* __restrict__ qbuf, const short* __restrict__ kp,
               const short* __restrict__ vt, short* __restrict__ oout, int causal)
{
    const int qt = blockIdx.x, bh = blockIdx.y;
    const int b = bh / 12, h = bh % 12;
    const int t = threadIdx.x, lane = t & 63, w = t >> 6;

    __shared__ short Ks[2][64 * 64];
    __shared__ short Vs[2][64 * 64];
    __shared__ short Plds[4][16][72];

    const int nrow = lane & 15;
    const int kch  = (lane >> 4) * 8;
    const int swz  = (lane & 7) << 3;

    short8 aq[2];
    {
        const short* qrow = qbuf + ((size_t)(b * LSEQ) + qt * 64 + w * 16 + nrow) * 768 + h * 64 + kch;
        aq[0] = *(const short8*)qrow;
        aq[1] = *(const short8*)(qrow + 32);
    }

    float m[4], lsum[4];
    floatx4 oacc[4];
#pragma unroll
    for (int r = 0; r < 4; ++r) { m[r] = -3e38f; lsum[r] = 0.f; }
#pragma unroll
    for (int j = 0; j < 4; ++j) oacc[j] = (floatx4){0.f, 0.f, 0.f, 0.f};

    const int ktend = causal ? qt : 8;
    const short* ksrc = kp + ((size_t)bh * LSEQ) * 64;
    const short* vsrc = vt + ((size_t)bh * 64) * LSEQ;

#define STAGE_KV(buf, kt)                                                             \
    {                                                                                 \
        const short* kt_src = ksrc + (size_t)((kt) * 64) * 64;                        \
        GLDS16(kt_src + (size_t)t * 8,         &Ks[buf][(size_t)t * 8]);              \
        GLDS16(kt_src + (size_t)(t + 256) * 8, &Ks[buf][(size_t)(t + 256) * 8]);      \
        GLDS16(vsrc + (size_t)(t >> 3) * LSEQ + (kt) * 64 + (t & 7) * 8,              \
               &Vs[buf][(size_t)t * 8]);                                              \
        GLDS16(vsrc + (size_t)((t + 256) >> 3) * LSEQ + (kt) * 64 + (t & 7) * 8,      \
               &Vs[buf][(size_t)(t + 256) * 8]);                                      \
    }

    STAGE_KV(0, 0);
    asm volatile("s_waitcnt vmcnt(0)" ::: "memory");
    __builtin_amdgcn_sched_barrier(0);
    __builtin_amdgcn_s_barrier();

    for (int kt = 0; kt <= ktend; ++kt) {
        const int cur = kt & 1;
        if (kt < ktend) STAGE_KV(cur ^ 1, kt + 1);

        floatx4 sc[4];
#pragma unroll
        for (int j = 0; j < 4; ++j) sc[j] = (floatx4){0.f, 0.f, 0.f, 0.f};
        __builtin_amdgcn_s_setprio(1);
#pragma unroll
        for (int s = 0; s < 2; ++s) {
#pragma unroll
            for (int j = 0; j < 4; ++j) {
                short8 bk = *(const short8*)&Ks[cur][(16 * j + nrow) * 64 + ((kch + 32 * s) ^ swz)];
                sc[j] = __builtin_amdgcn_mfma_f32_16x16x32_bf16(aq[s], bk, sc[j], 0, 0, 0);
            }
        }
        __builtin_amdgcn_s_setprio(0);
        float sv[4][4];
#pragma unroll
        for (int j = 0; j < 4; ++j)
#pragma unroll
            for (int r = 0; r < 4; ++r) {
                float v = sc[j][r] * 0.125f;
                if (causal && kt == qt) {
                    int key = kt * 64 + 16 * j + nrow;
                    int qr  = qt * 64 + w * 16 + (lane >> 4) * 4 + r;
                    if (key > qr) v = -1e12f;
                }
                sv[j][r] = v;
            }
#pragma unroll
        for (int r = 0; r < 4; ++r) {
            float tm = fmaxf(fmaxf(sv[0][r], sv[1][r]), fmaxf(sv[2][r], sv[3][r]));
            tm = fmaxf(tm, __shfl_xor(tm, 1, 64));
            tm = fmaxf(tm, __shfl_xor(tm, 2, 64));
            tm = fmaxf(tm, __shfl_xor(tm, 4, 64));
            tm = fmaxf(tm, __shfl_xor(tm, 8, 64));
            float nm = fmaxf(m[r], tm);
            float c  = __expf(m[r] - nm);
            m[r] = nm;
            float ps = 0.f;
#pragma unroll
            for (int j = 0; j < 4; ++j) {
                float p = __expf(sv[j][r] - nm);
                sv[j][r] = p;
                ps += p;
            }
            lsum[r] = lsum[r] * c + ps;
#pragma unroll
            for (int j = 0; j < 4; ++j) oacc[j][r] *= c;
        }
#pragma unroll
        for (int j = 0; j < 4; ++j)
#pragma unroll
            for (int r = 0; r < 4; ++r)
                Plds[w][(lane >> 4) * 4 + r][16 * j + nrow] = f2b(sv[j][r]);
        short8 ap[2];
#pragma unroll
        for (int s = 0; s < 2; ++s)
            ap[s] = *(const short8*)&Plds[w][nrow][kch + 32 * s];
        __builtin_amdgcn_s_setprio(1);
#pragma unroll
        for (int s = 0; s < 2; ++s) {
#pragma unroll
            for (int j = 0; j < 4; ++j) {
                short8 bv = *(const short8*)&Vs[cur][(16 * j + nrow) * 64 + ((kch + 32 * s) ^ swz)];
                oacc[j] = __builtin_amdgcn_mfma_f32_16x16x32_bf16(ap[s], bv, oacc[j], 0, 0, 0);
            }
        }
        __builtin_amdgcn_s_setprio(0);
        if (kt < ktend) {
            asm volatile("s_waitcnt vmcnt(0)" ::: "memory");
            __builtin_amdgcn_sched_barrier(0);
            __builtin_amdgcn_s_barrier();
        }
    }
#undef STAGE_KV

    float inv[4];
#pragma unroll
    for (int r = 0; r < 4; ++r) {
        float L = lsum[r];
        L += __shfl_xor(L, 1, 64);
        L += __shfl_xor(L, 2, 64);
        L += __shfl_xor(L, 4, 64);
        L += __shfl_xor(L, 8, 64);
        inv[r] = 1.f / L;
    }
#pragma unroll
    for (int j = 0; j < 4; ++j)
#pragma unroll
        for (int r = 0; r < 4; ++r) {
            size_t lq = (size_t)qt * 64 + w * 16 + (lane >> 4) * 4 + r;
            oout[((size_t)bh * LSEQ + lq) * 64 + 16 * j + nrow] = f2b(oacc[j][r] * inv[r]);
        }
}

// ---------------- transposes ----------------
__global__ void transpose_f2b(const float* __restrict__ in, short* __restrict__ out,
                              int R, int C, long long ibs, long long obs)
{
    __shared__ float tile[32][33];
    const int b = blockIdx.z;
    const float* inb = in + (long long)b * ibs;
    short* outb = out + (long long)b * obs;
    const int r0 = blockIdx.y * 32, c0 = blockIdx.x * 32;
    const int tx = threadIdx.x, ty = threadIdx.y;
#pragma unroll
    for (int i = 0; i < 32; i += 8) tile[ty + i][tx] = inb[(size_t)(r0 + ty + i) * C + c0 + tx];
    __syncthreads();
#pragma unroll
    for (int i = 0; i < 32; i += 8) outb[(size_t)(c0 + ty + i) * R + r0 + tx] = f2b(tile[tx][ty + i]);
}

__global__ void transpose_f2f(const float* __restrict__ in, float* __restrict__ out,
                              int R, int C, long long ibs, long long obs)
{
    __shared__ float tile[32][33];
    const int b = blockIdx.z;
    const float* inb = in + (long long)b * ibs;
    float* outb = out + (long long)b * obs;
    const int r0 = blockIdx.y * 32, c0 = blockIdx.x * 32;
    const int tx = threadIdx.x, ty = threadIdx.y;
#pragma unroll
    for (int i = 0; i < 32; i += 8) tile[ty + i][tx] = inb[(size_t)(r0 + ty + i) * C + c0 + tx];
    __syncthreads();
#pragma unroll
    for (int i = 0; i < 32; i += 8) outb[(size_t)(c0 + ty + i) * R + r0 + tx] = tile[tx][ty + i];
}

// ---------------- misc small kernels ----------------
__global__ void concat_qkv_bias(const float* __restrict__ bq, const float* __restrict__ bk,
                                const float* __restrict__ bv, float* __restrict__ out)
{
    int i = blockIdx.x * 256 + threadIdx.x;
    int layer = i / 2304, j = i % 2304;
    float v;
    if (j < 768)       v = bq[layer * 768 + j];
    else if (j < 1536) v = bk[layer * 768 + j - 768];
    else               v = bv[layer * 768 + j - 1536];
    out[i] = v;
}

__global__ void im2col_kernel(const float* __restrict__ x, short* __restrict__ xcol)
{
    const size_t idx = (size_t)blockIdx.x * 256 + threadIdx.x;
    const int k = (int)(idx % 768);
    const size_t m = idx / 768;
    const int c  = k >> 8;
    const int ky = (k >> 4) & 15;
    const int kx = k & 15;
    const int b  = (int)(m / 576);
    const int l  = (int)(m % 576);
    const int ph = l / 24, pw = l % 24;
    xcol[idx] = f2b(x[((size_t)(b * 3 + c) * 384 + ph * 16 + ky) * 384 + pw * 16 + kx]);
}

__global__ void cast_f32_b16(const float* __restrict__ in, short* __restrict__ out, int n)
{
    int i = blockIdx.x * 256 + threadIdx.x;
    if (i < n) out[i] = f2b(in[i]);
}

// ---------------- host launcher ----------------
extern "C" void kernel_launch(void* const* d_in, const int* in_sizes, int n_in,
                              void* d_out, int out_size, void* d_ws, size_t ws_size,
                              hipStream_t stream)
{
    const float* x      = (const float*)d_in[0];
    const float* conv_w = (const float*)d_in[1];
    const float* conv_b = (const float*)d_in[2];
    const float* pos    = (const float*)d_in[3];
    const float* ln0_s  = (const float*)d_in[4];
    const float* ln0_b  = (const float*)d_in[5];
    const float* Wq     = (const float*)d_in[6];
    const float* bq     = (const float*)d_in[7];
    const float* Wk     = (const float*)d_in[8];
    const float* bk     = (const float*)d_in[9];
    const float* Wv     = (const float*)d_in[10];
    const float* bv     = (const float*)d_in[11];
    const float* Wo     = (const float*)d_in[12];
    const float* bo     = (const float*)d_in[13];
    const float* ln1_s  = (const float*)d_in[14];
    const float* ln1_b  = (const float*)d_in[15];
    const float* W1     = (const float*)d_in[16];
    const float* b1     = (const float*)d_in[17];
    const float* W2     = (const float*)d_in[18];
    const float* b2     = (const float*)d_in[19];
    const float* proj_w = (const float*)d_in[20];
    const float* proj_b = (const float*)d_in[21];

    char* ws = (char*)d_ws;
    short* qkvT  = (short*)(ws);                    // [8][2304][768] bf16
    short* woT   = (short*)(ws + 28311552);         // [8][768][768]
    short* w1T   = (short*)(ws + 37748736);         // [8][3072][768]
    short* w2T   = (short*)(ws + 75497472);         // [8][768][3072]
    short* projT = (short*)(ws + 113246208);        // [768][768]
    float* qkvb  = (float*)(ws + 114425856);        // [8][2304] f32
    short* tmpA  = (short*)(ws + 114499584);        // xcol / m1 bf16 [4608][3072]; kp/vt overlay; yf f32
    float* h     = (float*)(ws + 142811136);        // residual stream f32 [4608][768]
    short* xn    = (short*)(ws + 156966912);        // LN0 out bf16; hb at end
    short* xrb   = (short*)(ws + 164044800);        // LN1 out bf16
    short* qbuf  = (short*)(ws + 185278464);        // Q [4608][768] bf16
    short* o     = (short*)(ws + 206512128);        // attn out (scrambled) bf16
    short* convB = (short*)(ws + 213590016);        // conv_w cast bf16 [768][768]

    short* kp = tmpA;                               // [96][576][64] bf16 (overlay)
    short* vt = tmpA + 3538944;                     // [96][64][576] bf16

    dim3 tb(32, 8);
    transpose_f2b<<<dim3(24, 24, 8), tb, 0, stream>>>(Wq, qkvT,           768, 768, 589824, 1769472);
    transpose_f2b<<<dim3(24, 24, 8), tb, 0, stream>>>(Wk, qkvT + 589824,  768, 768, 589824, 1769472);
    transpose_f2b<<<dim3(24, 24, 8), tb, 0, stream>>>(Wv, qkvT + 1179648, 768, 768, 589824, 1769472);
    transpose_f2b<<<dim3(24, 24, 8), tb, 0, stream>>>(Wo, woT,            768, 768, 589824, 589824);
    transpose_f2b<<<dim3(96, 24, 8), tb, 0, stream>>>(W1, w1T,            768, 3072, 2359296, 2359296);
    transpose_f2b<<<dim3(24, 96, 8), tb, 0, stream>>>(W2, w2T,            3072, 768, 2359296, 2359296);
    transpose_f2b<<<dim3(24, 24, 1), tb, 0, stream>>>(proj_w, projT,      768, 768, 0, 0);
    cast_f32_b16<<<2304, 256, 0, stream>>>(conv_w, convB, 589824);
    concat_qkv_bias<<<72, 256, 0, stream>>>(bq, bk, bv, qkvb);

    // patch embed: im2col + GEMM(convB as Bt) + conv_b + pos  -> h (f32)
    im2col_kernel<<<13824, 256, 0, stream>>>(x, tmpA);
    gemm_bt<3, 0, true, false, 1, false><<<dim3(6, 72), 256, 0, stream>>>(
        tmpA, convB, conv_b, pos, nullptr, h, nullptr, nullptr, 768, 768);

    for (int i = 0; i < NLAYERS; ++i) {
        ln_kernel<<<4608, 256, 0, stream>>>(h, ln0_s + i * 768, ln0_b + i * 768, xn);
        // qkv GEMM with fused split epilogue: Q->qbuf, K->kp (swz), V->vt (transposed+swz)
        gemm_bt<2, 0, false, false, 0, true><<<dim3(18, 72), 256, 0, stream>>>(
            xn, qkvT + (size_t)i * 1769472, qkvb + i * 2304, nullptr, nullptr, qbuf, kp, vt, 2304, 768);
        attn_mfma<<<dim3(9, 96), 256, 0, stream>>>(qbuf, kp, vt, o, i == 0 ? 1 : 0);
        gemm_bt<3, 1, false, false, 1, false><<<dim3(6, 72), 256, 0, stream>>>(
            o, woT + (size_t)i * 589824, bo + i * 768, nullptr, h, h, nullptr, nullptr, 768, 768);
        ln_kernel<<<4608, 256, 0, stream>>>(h, ln1_s + i * 768, ln1_b + i * 768, xrb);
        gemm_bt<2, 0, false, true, 0, false><<<dim3(24, 72), 256, 0, stream>>>(
            xrb, w1T + (size_t)i * 2359296, b1 + i * 3072, nullptr, nullptr, tmpA, nullptr, nullptr, 3072, 768);
        if (i < NLAYERS - 1) {
            gemm_bt<3, 2, false, false, 1, false><<<dim3(6, 72), 256, 0, stream>>>(
                tmpA, w2T + (size_t)i * 2359296, b2 + i * 768, nullptr, xrb, h, nullptr, nullptr, 768, 3072);
        } else {
            // last layer: also emit bf16 copy of h for the final projection (fused cast)
            gemm_bt<3, 2, false, false, 2, false><<<dim3(6, 72), 256, 0, stream>>>(
                tmpA, w2T + (size_t)i * 2359296, b2 + i * 768, nullptr, xrb, h, xn, nullptr, 768, 3072);
        }
    }

    // final projection + output scramble (B, L, CPP) -> (B, CPP, L) flat
    short* hb = xn;              // bf16 copy of final h (written by layer-7 W2 epilogue)
    float* yf = (float*)tmpA;
    gemm_bt<3, 0, false, false, 1, false><<<dim3(6, 72), 256, 0, stream>>>(
        hb, projT, proj_b, nullptr, nullptr, yf, nullptr, nullptr, 768, 768);
    transpose_f2f<<<dim3(24, 18, 8), tb, 0, stream>>>(yf, (float*)d_out, 576, 768, 442368, 442368);
}

// Round 14
// 1592.832 us; speedup vs baseline: 1.1176x; 1.0346x over previous
//
#include <hip/hip_runtime.h>
#include <hip/hip_bf16.h>
#include <stdint.h>

#define NLAYERS 8
#define LSEQ 576
#define EMB 768
#define NHEAD 12
#define HDIM 64
#define FFDIM 3072
#define BLROWS 4608   // B*L

typedef __attribute__((ext_vector_type(8))) short short8;
typedef __attribute__((ext_vector_type(4))) short short4v;
typedef __attribute__((ext_vector_type(4))) float floatx4;

__device__ __forceinline__ float b2f(short s) {
    union { float f; uint32_t u; } x; x.u = ((uint32_t)(uint16_t)s) << 16; return x.f;
}
__device__ __forceinline__ short f2b(float f) {
    union { float f; uint32_t u; } x; x.f = f;
    uint32_t r = x.u + 0x7fffu + ((x.u >> 16) & 1u);
    return (short)(r >> 16);
}

#define GLDS16(gp, lp) __builtin_amdgcn_global_load_lds( \
    (const __attribute__((address_space(1))) void*)(gp), \
    (__attribute__((address_space(3))) void*)(lp), 16, 0, 0)

// bijective XCD-chunked remap (m204)
__device__ __forceinline__ void xcd_remap(int& bx, int& by) {
    const int gx = gridDim.x;
    const int n  = gx * gridDim.y;
    const int orig = by * gx + bx;
    const int q = n >> 3, r = n & 7;
    const int xcd = orig & 7;
    const int wgid = (xcd < r ? xcd * (q + 1) : r * (q + 1) + (xcd - r) * q) + (orig >> 3);
    bx = wgid % gx;
    by = wgid / gx;
}

// ---------------- GEMM: C[M,N] = A[M,K](bf16) * Bt[N,K]^T (bf16) + epilogue ----------------
// 64x128 tile, BK=64. DEPTH=2: dbuf + full-drain barrier. DEPTH=3: counted vmcnt(6) (T4).
// T2 swizzle via pre-swizzled global source (rule 21). 4 waves, 2x2 of 32x64 per wave.
// RES: 0 none, 1 f32 residual, 2 bf16 residual.
// OUTM: 0 bf16, 1 f32, 2 f32 + bf16 copy into aux_kp.
// QKV: split epilogue -> Q (Cout, stride 768), K -> aux_kp (swz), V -> aux_vt (transposed+swz).
template<int DEPTH, int RES, bool ADD_POS, bool LEAKY, int OUTM, bool QKV>
__global__ __launch_bounds__(256)
void gemm_bt(const short* __restrict__ A, const short* __restrict__ Bt,
             const float* __restrict__ bias, const float* __restrict__ pos,
             const void* __restrict__ res, void* __restrict__ Cout,
             short* __restrict__ aux_kp, short* __restrict__ aux_vt,
             int N, int K)
{
    __shared__ short As[DEPTH * 64 * 64];
    __shared__ short Bs[DEPTH * 128 * 64];
    int bx = blockIdx.x, by = blockIdx.y;
    xcd_remap(bx, by);
    const int t    = threadIdx.x;
    const int lane = t & 63;
    const int w    = t >> 6;
    const int m0   = by * 64;
    const int n0   = bx * 128;
    const int wm   = (w >> 1) * 32;
    const int wn   = (w & 1) * 64;

    floatx4 acc[2][4];
#pragma unroll
    for (int i = 0; i < 2; ++i)
#pragma unroll
        for (int j = 0; j < 4; ++j)
            acc[i][j] = (floatx4){0.f, 0.f, 0.f, 0.f};

    const int srow = t >> 3;
    const int sch  = t & 7;
    const short* Ag = A  + (size_t)m0 * K;
    const short* Bg = Bt + (size_t)n0 * K;
    const int nt = K >> 6;

#define STAGE(buf, k0)                                                              \
    {                                                                               \
        _Pragma("unroll")                                                           \
        for (int i = 0; i < 2; ++i) {                                               \
            int row = srow + i * 32;                                                \
            GLDS16(Ag + (size_t)row * K + (k0) + ((sch ^ (row & 7)) << 3),          \
                   &As[(buf) * 4096 + (size_t)(t + i * 256) * 8]);                  \
        }                                                                           \
        _Pragma("unroll")                                                           \
        for (int i = 0; i < 4; ++i) {                                               \
            int row = srow + i * 32;                                                \
            GLDS16(Bg + (size_t)row * K + (k0) + ((sch ^ (row & 7)) << 3),          \
                   &Bs[(buf) * 8192 + (size_t)(t + i * 256) * 8]);                  \
        }                                                                           \
    }

#define COMPUTE(buf)                                                                \
    {                                                                               \
        _Pragma("unroll")                                                           \
        for (int ks = 0; ks < 2; ++ks) {                                            \
            short8 af[2], bf[4];                                                    \
            _Pragma("unroll")                                                       \
            for (int i = 0; i < 2; ++i) {                                           \
                int row = wm + i * 16 + (lane & 15);                                \
                int ch  = (ks * 4 + (lane >> 4)) ^ (row & 7);                       \
                af[i] = *(const short8*)&As[(buf) * 4096 + row * 64 + ch * 8];      \
            }                                                                       \
            _Pragma("unroll")                                                       \
            for (int j = 0; j < 4; ++j) {                                           \
                int row = wn + j * 16 + (lane & 15);                                \
                int ch  = (ks * 4 + (lane >> 4)) ^ (row & 7);                       \
                bf[j] = *(const short8*)&Bs[(buf) * 8192 + row * 64 + ch * 8];      \
            }                                                                       \
            _Pragma("unroll")                                                       \
            for (int i = 0; i < 2; ++i)                                             \
                _Pragma("unroll")                                                   \
                for (int j = 0; j < 4; ++j)                                         \
                    acc[i][j] = __builtin_amdgcn_mfma_f32_16x16x32_bf16(            \
                        af[i], bf[j], acc[i][j], 0, 0, 0);                          \
        }                                                                           \
    }

    if constexpr (DEPTH == 2) {
        STAGE(0, 0);
        __syncthreads();
        int cur = 0;
        for (int k0 = 0; k0 < K; k0 += 64) {
            if (k0 + 64 < K) STAGE(cur ^ 1, k0 + 64);
            COMPUTE(cur);
            __syncthreads();
            cur ^= 1;
        }
    } else {
        STAGE(0, 0);
        STAGE(1, 64);
        asm volatile("s_waitcnt vmcnt(6)" ::: "memory");
        __builtin_amdgcn_sched_barrier(0);
        __builtin_amdgcn_s_barrier();
        int cur = 0, stg = 2;
        for (int tt = 0; tt < nt; ++tt) {
            if (tt + 2 < nt) STAGE(stg, (tt + 2) << 6);
            COMPUTE(cur);
            if (tt + 1 < nt) {
                if (tt + 2 < nt) { asm volatile("s_waitcnt vmcnt(6)" ::: "memory"); }
                else             { asm volatile("s_waitcnt vmcnt(0)" ::: "memory"); }
                __builtin_amdgcn_sched_barrier(0);
                __builtin_amdgcn_s_barrier();
                __builtin_amdgcn_sched_barrier(0);
            }
            cur = (cur + 1 == DEPTH) ? 0 : cur + 1;
            stg = (stg + 1 == DEPTH) ? 0 : stg + 1;
        }
    }
#undef STAGE
#undef COMPUTE

    const int colb = n0 + wn + (lane & 15);
    const int rowb = m0 + wm + ((lane >> 4) * 4);
#pragma unroll
    for (int i = 0; i < 2; ++i) {
#pragma unroll
        for (int j = 0; j < 4; ++j) {
            const int col = colb + j * 16;
            const float bv = bias[col];
#pragma unroll
            for (int r = 0; r < 4; ++r) {
                const int row = rowb + i * 16 + r;
                float v = acc[i][j][r] + bv;
                if constexpr (ADD_POS) v += pos[(size_t)(row % LSEQ) * N + col];
                if constexpr (RES == 1) v += ((const float*)res)[(size_t)row * N + col];
                if constexpr (RES == 2) v += b2f(((const short*)res)[(size_t)row * N + col]);
                if constexpr (LEAKY)   v = v >= 0.f ? v : 0.01f * v;
                if constexpr (QKV) {
                    const int b = row / LSEQ, l = row % LSEQ;
                    const short sv16 = f2b(v);
                    if (col < 768) {
                        ((short*)Cout)[(size_t)row * 768 + col] = sv16;
                    } else if (col < 1536) {
                        const int d = col - 768, hh = d >> 6, dd = d & 63;
                        const size_t bh = (size_t)b * 12 + hh;
                        aux_kp[(bh * LSEQ + l) * 64 + (dd & 7) + (((dd >> 3) ^ (l & 7)) << 3)] = sv16;
                    } else {
                        const int d = col - 1536, hh = d >> 6, dd = d & 63;
                        const size_t bh = (size_t)b * 12 + hh;
                        aux_vt[(bh * 64 + dd) * LSEQ + (l & ~63) + ((l & 63) ^ ((dd & 7) << 3))] = sv16;
                    }
                } else if constexpr (OUTM == 1) {
                    ((float*)Cout)[(size_t)row * N + col] = v;
                } else if constexpr (OUTM == 2) {
                    ((float*)Cout)[(size_t)row * N + col] = v;
                    aux_kp[(size_t)row * N + col] = f2b(v);
                } else {
                    ((short*)Cout)[(size_t)row * N + col] = f2b(v);
                }
            }
        }
    }
}

// ---------------- split-K x2 GEMM, 128x128 tile, BK=64, DEPTH=2 (64 KB LDS, 2 blocks/CU) ------
// 4 waves of 64x64 (8 ds_read : 16 MFMA per wave-ks -> half LDS-pipe pressure per FLOP).
// Raw f32 partials -> P0 (z=0) / P1 (z=1); epilogue deferred to combinek.
__global__ __launch_bounds__(256)
void gemm_sk2(const short* __restrict__ A, const short* __restrict__ Bt,
              float* __restrict__ P0, float* __restrict__ P1, int N, int K)
{
    __shared__ short As[2 * 128 * 64];    // 32 KB
    __shared__ short Bs[2 * 128 * 64];    // 32 KB
    int bx = blockIdx.x, by = blockIdx.y;
    xcd_remap(bx, by);
    const int t    = threadIdx.x;
    const int lane = t & 63;
    const int w    = t >> 6;
    const int m0   = by * 128;
    const int n0   = bx * 128;
    const int wm   = (w >> 1) * 64;
    const int wn   = (w & 1) * 64;
    const int klen  = K >> 1;
    const int kbase = blockIdx.z * klen;

    floatx4 acc[4][4];
#pragma unroll
    for (int i = 0; i < 4; ++i)
#pragma unroll
        for (int j = 0; j < 4; ++j)
            acc[i][j] = (floatx4){0.f, 0.f, 0.f, 0.f};

    const int srow = t >> 3;
    const int sch  = t & 7;
    const short* Ag = A  + (size_t)m0 * K + kbase;
    const short* Bg = Bt + (size_t)n0 * K + kbase;

#define STAGE(buf, k0)                                                              \
    {                                                                               \
        _Pragma("unroll")                                                           \
        for (int i = 0; i < 4; ++i) {                                               \
            int row = srow + i * 32;                                                \
            GLDS16(Ag + (size_t)row * K + (k0) + ((sch ^ (row & 7)) << 3),          \
                   &As[(buf) * 8192 + (size_t)(t + i * 256) * 8]);                  \
        }                                                                           \
        _Pragma("unroll")                                                           \
        for (int i = 0; i < 4; ++i) {                                               \
            int row = srow + i * 32;                                                \
            GLDS16(Bg + (size_t)row * K + (k0) + ((sch ^ (row & 7)) << 3),          \
                   &Bs[(buf) * 8192 + (size_t)(t + i * 256) * 8]);                  \
        }                                                                           \
    }

    STAGE(0, 0);
    __syncthreads();
    int cur = 0;
    for (int k0 = 0; k0 < klen; k0 += 64) {
        if (k0 + 64 < klen) STAGE(cur ^ 1, k0 + 64);
#pragma unroll
        for (int ks = 0; ks < 2; ++ks) {
            short8 af[4], bf[4];
#pragma unroll
            for (int i = 0; i < 4; ++i) {
                int row = wm + i * 16 + (lane & 15);
                int ch  = (ks * 4 + (lane >> 4)) ^ (row & 7);
                af[i] = *(const short8*)&As[cur * 8192 + row * 64 + ch * 8];
            }
#pragma unroll
            for (int j = 0; j < 4; ++j) {
                int row = wn + j * 16 + (lane & 15);
                int ch  = (ks * 4 + (lane >> 4)) ^ (row & 7);
                bf[j] = *(const short8*)&Bs[cur * 8192 + row * 64 + ch * 8];
            }
#pragma unroll
            for (int i = 0; i < 4; ++i)
#pragma unroll
                for (int j = 0; j < 4; ++j)
                    acc[i][j] = __builtin_amdgcn_mfma_f32_16x16x32_bf16(af[i], bf[j], acc[i][j], 0, 0, 0);
        }
        __syncthreads();
        cur ^= 1;
    }
#undef STAGE

    float* P = blockIdx.z ? P1 : P0;
    const int colb = n0 + wn + (lane & 15);
    const int rowb = m0 + wm + ((lane >> 4) * 4);
#pragma unroll
    for (int i = 0; i < 4; ++i)
#pragma unroll
        for (int j = 0; j < 4; ++j)
#pragma unroll
            for (int r = 0; r < 4; ++r)
                P[(size_t)(rowb + i * 16 + r) * N + colb + j * 16] = acc[i][j][r];
}

// ---------------- split-K combine + full epilogue (N=768 shapes). 4 el/thread ----------------
// RES: 0/1/2 as gemm_bt. OUTM: 1 f32 out, 2 f32 + bf16 copy.
template<int RES, bool ADD_POS, int OUTM>
__global__ __launch_bounds__(256)
void combinek(const float* __restrict__ P0, const float* __restrict__ P1,
              const float* __restrict__ bias, const float* __restrict__ pos,
              const void* __restrict__ res, float* __restrict__ out,
              short* __restrict__ auxb)
{
    const size_t i4 = ((size_t)blockIdx.x * 256 + threadIdx.x) * 4;   // < 4608*768
    const int row = (int)(i4 / 768);
    const int col = (int)(i4 % 768);
    floatx4 a = *(const floatx4*)&P0[i4];
    floatx4 b = *(const floatx4*)&P1[i4];
    floatx4 bv = *(const floatx4*)&bias[col];
    floatx4 v;
#pragma unroll
    for (int j = 0; j < 4; ++j) v[j] = a[j] + b[j] + bv[j];
    if constexpr (ADD_POS) {
        floatx4 p = *(const floatx4*)&pos[(size_t)(row % LSEQ) * 768 + col];
#pragma unroll
        for (int j = 0; j < 4; ++j) v[j] += p[j];
    }
    if constexpr (RES == 1) {
        floatx4 rr = *(const floatx4*)&((const float*)res)[i4];
#pragma unroll
        for (int j = 0; j < 4; ++j) v[j] += rr[j];
    }
    if constexpr (RES == 2) {
        short4v rr = *(const short4v*)&((const short*)res)[i4];
#pragma unroll
        for (int j = 0; j < 4; ++j) v[j] += b2f(rr[j]);
    }
    *(floatx4*)&out[i4] = v;
    if constexpr (OUTM == 2) {
        short4v ob;
#pragma unroll
        for (int j = 0; j < 4; ++j) ob[j] = f2b(v[j]);
        *(short4v*)&auxb[i4] = ob;
    }
}

// ---------------- LayerNorm over E=768, input f32, output bf16 ----------------
__global__ __launch_bounds__(256)
void ln_kernel(const float* __restrict__ h, const float* __restrict__ g,
               const float* __restrict__ bbias, short* __restrict__ outb)
{
    const int row = blockIdx.x;
    const float* x = h + (size_t)row * EMB;
    const int t = threadIdx.x;
    float v0 = x[t], v1 = x[t + 256], v2 = x[t + 512];
    float s  = v0 + v1 + v2;
    float ss = v0 * v0 + v1 * v1 + v2 * v2;
#pragma unroll
    for (int m = 1; m < 64; m <<= 1) {
        s  += __shfl_xor(s, m, 64);
        ss += __shfl_xor(ss, m, 64);
    }
    __shared__ float red[8];
    if ((t & 63) == 0) { red[t >> 6] = s; red[4 + (t >> 6)] = ss; }
    __syncthreads();
    float S  = red[0] + red[1] + red[2] + red[3];
    float SS = red[4] + red[5] + red[6] + red[7];
    float mean = S * (1.f / 768.f);
    float var  = SS * (1.f / 768.f) - mean * mean;
    float rstd = rsqrtf(var + 1e-5f);
    const size_t base = (size_t)row * EMB;
#pragma unroll
    for (int q = 0; q < 3; ++q) {
        int e = t + q * 256;
        float v = (q == 0 ? v0 : (q == 1 ? v1 : v2));
        float y = (v - mean) * rstd * g[e] + bbias[e];
        outb[base + e] = f2b(y);
    }
}

// ---------------- MFMA flash attention. grid (9 qtiles, 96 bh), block 256 = 4 waves ----------------
__global__ __launch_bounds__(256)
void attn_mfma(const short* __restrict__ qbuf, const short* __restrict__ kp,
               const short* __restrict__ vt, short* __restrict__ oout, int causal)
{
    const int qt = blockIdx.x, bh = blockIdx.y;
    const int b = bh / 12, h = bh % 12;
    const int t = threadIdx.x, lane = t & 63, w = t >> 6;

    __shared__ short Ks[64 * 64];
    __shared__ short Vs[64 * 64];
    __shared__ short Plds[4][16][72];

    const int nrow = lane & 15;
    const int kch  = (lane >> 4) * 8;
    const int swz  = (lane & 7) << 3;

    short8 aq[2];
    {
        const short* qrow = qbuf + ((size_t)(b * LSEQ) + qt * 64 + w * 16 + nrow) * 768 + h * 64 + kch;
        aq[0] = *(const short8*)qrow;
        aq[1] = *(const short8*)(qrow + 32);
    }

    float m[4], lsum[4];
    floatx4 oacc[4];
#pragma unroll
    for (int r = 0; r < 4; ++r) { m[r] = -3e38f; lsum[r] = 0.f; }
#pragma unroll
    for (int j = 0; j < 4; ++j) oacc[j] = (floatx4){0.f, 0.f, 0.f, 0.f};

    const int ktend = causal ? qt : 8;
    const short* ksrc = kp + ((size_t)bh * LSEQ) * 64;
    const short* vsrc = vt + ((size_t)bh * 64) * LSEQ;

    for (int kt = 0; kt <= ktend; ++kt) {
        __syncthreads();
        {
            const short* kt_src = ksrc + (size_t)(kt * 64) * 64;
            GLDS16(kt_src + (size_t)t * 8,          &Ks[(size_t)t * 8]);
            GLDS16(kt_src + (size_t)(t + 256) * 8,  &Ks[(size_t)(t + 256) * 8]);
            int f0 = t, f1 = t + 256;
            GLDS16(vsrc + (size_t)(f0 >> 3) * LSEQ + kt * 64 + (f0 & 7) * 8, &Vs[(size_t)f0 * 8]);
            GLDS16(vsrc + (size_t)(f1 >> 3) * LSEQ + kt * 64 + (f1 & 7) * 8, &Vs[(size_t)f1 * 8]);
        }
        __syncthreads();

        floatx4 sc[4];
#pragma unroll
        for (int j = 0; j < 4; ++j) sc[j] = (floatx4){0.f, 0.f, 0.f, 0.f};
#pragma unroll
        for (int s = 0; s < 2; ++s) {
#pragma unroll
            for (int j = 0; j < 4; ++j) {
                short8 bk = *(const short8*)&Ks[(16 * j + nrow) * 64 + ((kch + 32 * s) ^ swz)];
                sc[j] = __builtin_amdgcn_mfma_f32_16x16x32_bf16(aq[s], bk, sc[j], 0, 0, 0);
            }
        }
        float sv[4][4];
#pragma unroll
        for (int j = 0; j < 4; ++j)
#pragma unroll
            for (int r = 0; r < 4; ++r) {
                float v = sc[j][r] * 0.125f;
                if (causal && kt == qt) {
                    int key = kt * 64 + 16 * j + nrow;
                    int qr  = qt * 64 + w * 16 + (lane >> 4) * 4 + r;
                    if (key > qr) v = -1e12f;
                }
                sv[j][r] = v;
            }
#pragma unroll
        for (int r = 0; r < 4; ++r) {
            float tm = fmaxf(fmaxf(sv[0][r], sv[1][r]), fmaxf(sv[2][r], sv[3][r]));
            tm = fmaxf(tm, __shfl_xor(tm, 1, 64));
            tm = fmaxf(tm, __shfl_xor(tm, 2, 64));
            tm = fmaxf(tm, __shfl_xor(tm, 4, 64));
            tm = fmaxf(tm, __shfl_xor(tm, 8, 64));
            float nm = fmaxf(m[r], tm);
            float c  = __expf(m[r] - nm);
            m[r] = nm;
            float ps = 0.f;
#pragma unroll
            for (int j = 0; j < 4; ++j) {
                float p = __expf(sv[j][r] - nm);
                sv[j][r] = p;
                ps += p;
            }
            lsum[r] = lsum[r] * c + ps;
#pragma unroll
            for (int j = 0; j < 4; ++j) oacc[j][r] *= c;
        }
#pragma unroll
        for (int j = 0; j < 4; ++j)
#pragma unroll
            for (int r = 0; r < 4; ++r)
                Plds[w][(lane >> 4) * 4 + r][16 * j + nrow] = f2b(sv[j][r]);
        short8 ap[2];
#pragma unroll
        for (int s = 0; s < 2; ++s)
            ap[s] = *(const short8*)&Plds[w][nrow][kch + 32 * s];
#pragma unroll
        for (int s = 0; s < 2; ++s) {
#pragma unroll
            for (int j = 0; j < 4; ++j) {
                short8 bv = *(const short8*)&Vs[(16 * j + nrow) * 64 + ((kch + 32 * s) ^ swz)];
                oacc[j] = __builtin_amdgcn_mfma_f32_16x16x32_bf16(ap[s], bv, oacc[j], 0, 0, 0);
            }
        }
    }

    float inv[4];
#pragma unroll
    for (int r = 0; r < 4; ++r) {
        float L = lsum[r];
        L += __shfl_xor(L, 1, 64);
        L += __shfl_xor(L, 2, 64);
        L += __shfl_xor(L, 4, 64);
        L += __shfl_xor(L, 8, 64);
        inv[r] = 1.f / L;
    }
#pragma unroll
    for (int j = 0; j < 4; ++j)
#pragma unroll
        for (int r = 0; r < 4; ++r) {
            size_t lq = (size_t)qt * 64 + w * 16 + (lane >> 4) * 4 + r;
            oout[((size_t)bh * LSEQ + lq) * 64 + 16 * j + nrow] = f2b(oacc[j][r] * inv[r]);
        }
}

// ---------------- transposes ----------------
__global__ void transpose_f2b(const float* __restrict__ in, short* __restrict__ out,
                              int R, int C, long long ibs, long long obs)
{
    __shared__ float tile[32][33];
    const int b = blockIdx.z;
    const float* inb = in + (long long)b * ibs;
    short* outb = out + (long long)b * obs;
    const int r0 = blockIdx.y * 32, c0 = blockIdx.x * 32;
    const int tx = threadIdx.x, ty = threadIdx.y;
#pragma unroll
    for (int i = 0; i < 32; i += 8) tile[ty + i][tx] = inb[(size_t)(r0 + ty + i) * C + c0 + tx];
    __syncthreads();
#pragma unroll
    for (int i = 0; i < 32; i += 8) outb[(size_t)(c0 + ty + i) * R + r0 + tx] = f2b(tile[tx][ty + i]);
}

__global__ void transpose_f2f(const float* __restrict__ in, float* __restrict__ out,
                              int R, int C, long long ibs, long long obs)
{
    __shared__ float tile[32][33];
    const int b = blockIdx.z;
    const float* inb = in + (long long)b * ibs;
    float* outb = out + (long long)b * obs;
    const int r0 = blockIdx.y * 32, c0 = blockIdx.x * 32;
    const int tx = threadIdx.x, ty = threadIdx.y;
#pragma unroll
    for (int i = 0; i < 32; i += 8) tile[ty + i][tx] = inb[(size_t)(r0 + ty + i) * C + c0 + tx];
    __syncthreads();
#pragma unroll
    for (int i = 0; i < 32; i += 8) outb[(size_t)(c0 + ty + i) * R + r0 + tx] = tile[tx][ty + i];
}

// ---------------- misc small kernels ----------------
__global__ void concat_qkv_bias(const float* __restrict__ bq, const float* __restrict__ bk,
                                const float* __restrict__ bv, float* __restrict__ out)
{
    int i = blockIdx.x * 256 + threadIdx.x;
    int layer = i / 2304, j = i % 2304;
    float v;
    if (j < 768)       v = bq[layer * 768 + j];
    else if (j < 1536) v = bk[layer * 768 + j - 768];
    else               v = bv[layer * 768 + j - 1536];
    out[i] = v;
}

__global__ void im2col_kernel(const float* __restrict__ x, short* __restrict__ xcol)
{
    const size_t idx = (size_t)blockIdx.x * 256 + threadIdx.x;
    const int k = (int)(idx % 768);
    const size_t m = idx / 768;
    const int c  = k >> 8;
    const int ky = (k >> 4) & 15;
    const int kx = k & 15;
    const int b  = (int)(m / 576);
    const int l  = (int)(m % 576);
    const int ph = l / 24, pw = l % 24;
    xcol[idx] = f2b(x[((size_t)(b * 3 + c) * 384 + ph * 16 + ky) * 384 + pw * 16 + kx]);
}

__global__ void cast_f32_b16(const float* __restrict__ in, short* __restrict__ out, int n)
{
    int i = blockIdx.x * 256 + threadIdx.x;
    if (i < n) out[i] = f2b(in[i]);
}

// ---------------- host launcher ----------------
extern "C" void kernel_launch(void* const* d_in, const int* in_sizes, int n_in,
                              void* d_out, int out_size, void* d_ws, size_t ws_size,
                              hipStream_t stream)
{
    const float* x      = (const float*)d_in[0];
    const float* conv_w = (const float*)d_in[1];
    const float* conv_b = (const float*)d_in[2];
    const float* pos    = (const float*)d_in[3];
    const float* ln0_s  = (const float*)d_in[4];
    const float* ln0_b  = (const float*)d_in[5];
    const float* Wq     = (const float*)d_in[6];
    const float* bq     = (const float*)d_in[7];
    const float* Wk     = (const float*)d_in[8];
    const float* bk     = (const float*)d_in[9];
    const float* Wv     = (const float*)d_in[10];
    const float* bv     = (const float*)d_in[11];
    const float* Wo     = (const float*)d_in[12];
    const float* bo     = (const float*)d_in[13];
    const float* ln1_s  = (const float*)d_in[14];
    const float* ln1_b  = (const float*)d_in[15];
    const float* W1     = (const float*)d_in[16];
    const float* b1     = (const float*)d_in[17];
    const float* W2     = (const float*)d_in[18];
    const float* b2     = (const float*)d_in[19];
    const float* proj_w = (const float*)d_in[20];
    const float* proj_b = (const float*)d_in[21];

    char* ws = (char*)d_ws;
    short* qkvT  = (short*)(ws);                    // [8][2304][768] bf16
    short* woT   = (short*)(ws + 28311552);         // [8][768][768]
    short* w1T   = (short*)(ws + 37748736);         // [8][3072][768]
    short* w2T   = (short*)(ws + 75497472);         // [8][768][3072]
    short* projT = (short*)(ws + 113246208);        // [768][768]
    float* qkvb  = (float*)(ws + 114425856);        // [8][2304] f32
    short* tmpA  = (short*)(ws + 114499584);        // xcol / m1 bf16 [4608][3072]; kp/vt overlay; yf f32
    float* h     = (float*)(ws + 142811136);        // residual stream f32 [4608][768]
    short* xn    = (short*)(ws + 156966912);        // LN0 out bf16; hb at end
    short* xrb   = (short*)(ws + 164044800);        // LN1 out bf16
    short* qbuf  = (short*)(ws + 185278464);        // Q [4608][768] bf16; P1 (f32) overlay
    short* o     = (short*)(ws + 206512128);        // attn out (scrambled) bf16
    short* convB = (short*)(ws + 213590016);        // conv_w cast bf16 [768][768]

    short* kp = tmpA;                               // [96][576][64] bf16 (overlay)
    short* vt = tmpA + 3538944;                     // [96][64][576] bf16
    float* P1 = (float*)qbuf;                       // split-K partial (qbuf dead at W2)

    dim3 tb(32, 8);
    transpose_f2b<<<dim3(24, 24, 8), tb, 0, stream>>>(Wq, qkvT,           768, 768, 589824, 1769472);
    transpose_f2b<<<dim3(24, 24, 8), tb, 0, stream>>>(Wk, qkvT + 589824,  768, 768, 589824, 1769472);
    transpose_f2b<<<dim3(24, 24, 8), tb, 0, stream>>>(Wv, qkvT + 1179648, 768, 768, 589824, 1769472);
    transpose_f2b<<<dim3(24, 24, 8), tb, 0, stream>>>(Wo, woT,            768, 768, 589824, 589824);
    transpose_f2b<<<dim3(96, 24, 8), tb, 0, stream>>>(W1, w1T,            768, 3072, 2359296, 2359296);
    transpose_f2b<<<dim3(24, 96, 8), tb, 0, stream>>>(W2, w2T,            3072, 768, 2359296, 2359296);
    transpose_f2b<<<dim3(24, 24, 1), tb, 0, stream>>>(proj_w, projT,      768, 768, 0, 0);
    cast_f32_b16<<<2304, 256, 0, stream>>>(conv_w, convB, 589824);
    concat_qkv_bias<<<72, 256, 0, stream>>>(bq, bk, bv, qkvb);

    // patch embed: im2col + GEMM(convB as Bt) + conv_b + pos  -> h (f32)
    im2col_kernel<<<13824, 256, 0, stream>>>(x, tmpA);
    gemm_bt<3, 0, true, false, 1, false><<<dim3(6, 72), 256, 0, stream>>>(
        tmpA, convB, conv_b, pos, nullptr, h, nullptr, nullptr, 768, 768);

    for (int i = 0; i < NLAYERS; ++i) {
        ln_kernel<<<4608, 256, 0, stream>>>(h, ln0_s + i * 768, ln0_b + i * 768, xn);
        // qkv GEMM with fused split epilogue: Q->qbuf, K->kp (swz), V->vt (transposed+swz)
        gemm_bt<2, 0, false, false, 0, true><<<dim3(18, 72), 256, 0, stream>>>(
            xn, qkvT + (size_t)i * 1769472, qkvb + i * 2304, nullptr, nullptr, qbuf, kp, vt, 2304, 768);
        attn_mfma<<<dim3(9, 96), 256, 0, stream>>>(qbuf, kp, vt, o, i == 0 ? 1 : 0);
        gemm_bt<3, 1, false, false, 1, false><<<dim3(6, 72), 256, 0, stream>>>(
            o, woT + (size_t)i * 589824, bo + i * 768, nullptr, h, h, nullptr, nullptr, 768, 768);
        ln_kernel<<<4608, 256, 0, stream>>>(h, ln1_s + i * 768, ln1_b + i * 768, xrb);
        gemm_bt<2, 0, false, true, 0, false><<<dim3(24, 72), 256, 0, stream>>>(
            xrb, w1T + (size_t)i * 2359296, b1 + i * 3072, nullptr, nullptr, tmpA, nullptr, nullptr, 3072, 768);
        // W2: 128^2-tile split-K x2 (P0=h dead after LN1, P1=qbuf dead after attn) + combine
        gemm_sk2<<<dim3(6, 36, 2), 256, 0, stream>>>(
            tmpA, w2T + (size_t)i * 2359296, h, P1, 768, 3072);
        if (i < NLAYERS - 1) {
            combinek<2, false, 1><<<3456, 256, 0, stream>>>(h, P1, b2 + i * 768, nullptr, xrb, h, nullptr);
        } else {
            // last layer: also emit bf16 copy of h for the final projection (fused cast)
            combinek<2, false, 2><<<3456, 256, 0, stream>>>(h, P1, b2 + i * 768, nullptr, xrb, h, xn);
        }
    }

    // final projection + output scramble (B, L, CPP) -> (B, CPP, L) flat
    short* hb = xn;              // bf16 copy of final h (written by layer-7 W2 combine)
    float* yf = (float*)tmpA;
    gemm_bt<3, 0, false, false, 1, false><<<dim3(6, 72), 256, 0, stream>>>(
        hb, projT, proj_b, nullptr, nullptr, yf, nullptr, nullptr, 768, 768);
    transpose_f2f<<<dim3(24, 18, 8), tb, 0, stream>>>(yf, (float*)d_out, 576, 768, 442368, 442368);
}